// Round 2
// baseline (306.328 us; speedup 1.0000x reference)
//
#include <hip/hip_runtime.h>
#include <cmath>

// x[32768, 256] fp32, codebook[1024, 256] fp32. Outputs fp32 flat:
// loss(1), z_q(8388608), perplexity(1), indices(32768)
#define NROWS 32768
#define DDIM  256
#define KCB   1024

// Split-fp16 (hi+lo) 3-term dot: dist error ~4e-5 sigma; TAU=0.02 is ~500x.
// Flag rate ~1e-3 -> fp64 rescan is a correctness net, rarely executed.
constexpr float TAU = 0.02f;
constexpr int BSTR = 264;      // validated conflict-free stride (528 B/row)

typedef _Float16 half8 __attribute__((ext_vector_type(8)));
typedef float floatx4 __attribute__((ext_vector_type(4)));

__global__ void init_kernel(double* __restrict__ sumsq, int* __restrict__ sumidx) {
  *sumsq = 0.0;
  *sumidx = 0;
}

// Exact codebook norms (fp64 -> fp32).
__global__ __launch_bounds__(64) void prep_kernel(const float* __restrict__ cb,
                                                  float* __restrict__ cn) {
  const int k = blockIdx.x, lane = threadIdx.x;
  float4 v = *(const float4*)(cb + (size_t)k * DDIM + lane * 4);
  double s = (double)v.x * v.x + (double)v.y * v.y
           + (double)v.z * v.z + (double)v.w * v.w;
  #pragma unroll
  for (int off = 32; off; off >>= 1) s += __shfl_down(s, off);
  if (lane == 0) cn[k] = (float)s;
}

// Block = 512 thr / 8 waves, 128 rows (16 rows/wave). Grid 256 = 1 block/CU
// -> 8 waves/CU = 2 waves/SIMD TLP. Live VGPRs ~130 (A hi/lo 64, vld 16,
// acc 8, mins 12) -> no spills under the 256-reg cap of launch_bounds(512,2).
// Stage = 32 codebook entries x 256 dims, {hi rows 0..31, lo rows 32..63}
// fp16 in 64xBSTR layout, double-buffered (67.6 KB). hi/lo computed on the
// fly from fp32 cb. dot = a_hi*b_hi + a_lo*b_hi + a_hi*b_lo (3 MFMA, fp32 acc).
// Pipeline per stage: write -> barrier -> issue loads(st+1) -> compute(st).
__global__ __launch_bounds__(512, 2) void fused_kernel(
    const float* __restrict__ x,
    const float* __restrict__ cb,
    const float* __restrict__ cn,
    float* __restrict__ zq_out,
    float* __restrict__ idx_out,
    double* __restrict__ sumsq,
    int* __restrict__ sumidx) {
  __shared__ __align__(16) _Float16 bs[2][64 * BSTR];  // 2 x 33.8 KB tiles
  __shared__ float cn_lds[KCB];
  __shared__ int   bidx[128];
  __shared__ float marg[128];
  __shared__ __align__(16) float xrow[DDIM];
  __shared__ int   flist[128];
  __shared__ int   nflag;
  __shared__ float wred[8];
  __shared__ double rv[8];
  __shared__ int    ri[8];

  const int tid = threadIdx.x;
  const int lane = tid & 63;
  const int w = tid >> 6;        // wave 0..7: rows w*16 .. +15
  const int q = lane >> 4;       // quad
  const int tx = lane & 15;
  const int row0 = blockIdx.x * 128;

  // ---- A fragments (hi+lo): lane holds x[row0+w*16+tx][s*32+q*8..+7] ----
  half8 a_hi[8], a_lo[8];
  {
    const float* xp = x + (size_t)(row0 + w * 16 + tx) * DDIM + q * 8;
    #pragma unroll
    for (int s = 0; s < 8; ++s) {
      float4 v0 = *(const float4*)(xp + s * 32);
      float4 v1 = *(const float4*)(xp + s * 32 + 4);
      half8 h, l;
      _Float16 t;
      t = (_Float16)v0.x; h[0] = t; l[0] = (_Float16)(v0.x - (float)t);
      t = (_Float16)v0.y; h[1] = t; l[1] = (_Float16)(v0.y - (float)t);
      t = (_Float16)v0.z; h[2] = t; l[2] = (_Float16)(v0.z - (float)t);
      t = (_Float16)v0.w; h[3] = t; l[3] = (_Float16)(v0.w - (float)t);
      t = (_Float16)v1.x; h[4] = t; l[4] = (_Float16)(v1.x - (float)t);
      t = (_Float16)v1.y; h[5] = t; l[5] = (_Float16)(v1.y - (float)t);
      t = (_Float16)v1.z; h[6] = t; l[6] = (_Float16)(v1.z - (float)t);
      t = (_Float16)v1.w; h[7] = t; l[7] = (_Float16)(v1.w - (float)t);
      a_hi[s] = h; a_lo[s] = l;
    }
  }
  #pragma unroll
  for (int i = 0; i < 2; ++i) cn_lds[tid + 512 * i] = cn[tid + 512 * i];
  if (tid == 0) nflag = 0;

  // stage ct covers entries ct*32..+31 (8192 floats). 32-B unit u = tid+512*i:
  // entry e = u>>5, dim chunk (u&31)*8..+7. Coalesced 32 B/thread loads.
  float4 vld[4];
  auto load_stage = [&](int ct) {
    #pragma unroll
    for (int i = 0; i < 2; ++i) {
      int u = tid + 512 * i;
      const float* p = cb + (size_t)ct * 8192 + (size_t)u * 8;
      vld[2 * i]     = *(const float4*)p;
      vld[2 * i + 1] = *(const float4*)(p + 4);
    }
  };
  auto write_stage = [&](int buf) {
    #pragma unroll
    for (int i = 0; i < 2; ++i) {
      int u = tid + 512 * i;
      int e = u >> 5, c = u & 31;
      float4 v0 = vld[2 * i], v1 = vld[2 * i + 1];
      half8 h, l;
      _Float16 t;
      t = (_Float16)v0.x; h[0] = t; l[0] = (_Float16)(v0.x - (float)t);
      t = (_Float16)v0.y; h[1] = t; l[1] = (_Float16)(v0.y - (float)t);
      t = (_Float16)v0.z; h[2] = t; l[2] = (_Float16)(v0.z - (float)t);
      t = (_Float16)v0.w; h[3] = t; l[3] = (_Float16)(v0.w - (float)t);
      t = (_Float16)v1.x; h[4] = t; l[4] = (_Float16)(v1.x - (float)t);
      t = (_Float16)v1.y; h[5] = t; l[5] = (_Float16)(v1.y - (float)t);
      t = (_Float16)v1.z; h[6] = t; l[6] = (_Float16)(v1.z - (float)t);
      t = (_Float16)v1.w; h[7] = t; l[7] = (_Float16)(v1.w - (float)t);
      *(half8*)&bs[buf][e * BSTR + c * 8] = h;         // hi rows 0..31
      *(half8*)&bs[buf][(32 + e) * BSTR + c * 8] = l;  // lo rows 32..63
    }
  };

  float minv[4], minv2[4];
  int mini[4];
  #pragma unroll
  for (int r = 0; r < 4; ++r) { minv[r] = INFINITY; minv2[r] = INFINITY; mini[r] = 0; }

  load_stage(0);
  for (int st = 0; st < 32; ++st) {
    const int buf = st & 1;
    write_stage(buf);            // consumes loads issued last iter (vmcnt wait)
    __syncthreads();             // tile visible; prev tile's readers done
    if (st + 1 < 32) load_stage(st + 1);   // in flight across compute(st)

    floatx4 acc[2];
    #pragma unroll
    for (int ci = 0; ci < 2; ++ci) acc[ci] = (floatx4){0.f, 0.f, 0.f, 0.f};

    #pragma unroll
    for (int s = 0; s < 8; ++s) {
      #pragma unroll
      for (int ci = 0; ci < 2; ++ci) {
        half8 bh = *(const half8*)&bs[buf][(ci * 16 + tx) * BSTR + (s * 4 + q) * 8];
        half8 bl = *(const half8*)&bs[buf][(32 + ci * 16 + tx) * BSTR + (s * 4 + q) * 8];
        acc[ci] = __builtin_amdgcn_mfma_f32_16x16x32_f16(a_hi[s], bh, acc[ci], 0, 0, 0);
        acc[ci] = __builtin_amdgcn_mfma_f32_16x16x32_f16(a_lo[s], bh, acc[ci], 0, 0, 0);
        acc[ci] = __builtin_amdgcn_mfma_f32_16x16x32_f16(a_hi[s], bl, acc[ci], 0, 0, 0);
      }
    }

    // epilogue: C/D layout col=lane&15, row=q*4+reg
    #pragma unroll
    for (int ci = 0; ci < 2; ++ci) {
      int col = st * 32 + ci * 16 + tx;
      float cnv = cn_lds[col];
      #pragma unroll
      for (int r = 0; r < 4; ++r) {
        float dist = cnv - 2.f * acc[ci][r];
        if (dist < minv[r]) {
          minv2[r] = minv[r];
          minv[r] = dist; mini[r] = col;
        } else if (dist < minv2[r]) {
          minv2[r] = dist;
        }
      }
    }
  }

  // merge (best, idx, second) across the 16 tx-lanes of each quad
  #pragma unroll
  for (int off = 8; off; off >>= 1) {
    #pragma unroll
    for (int r = 0; r < 4; ++r) {
      float ov  = __shfl_down(minv[r],  off, 16);
      int   oi  = __shfl_down(mini[r],  off, 16);
      float ov2 = __shfl_down(minv2[r], off, 16);
      if (ov < minv[r] || (ov == minv[r] && oi < mini[r])) {
        minv2[r] = fminf(minv[r], ov2);
        minv[r] = ov; mini[r] = oi;
      } else {
        minv2[r] = fminf(minv2[r], ov);
      }
    }
  }
  if (tx == 0) {
    #pragma unroll
    for (int r = 0; r < 4; ++r) {
      int R = w * 16 + q * 4 + r;
      bidx[R] = mini[r];
      marg[R] = minv2[r] - minv[r];
    }
  }
  __syncthreads();

  if (tid < 128 && marg[tid] < TAU) {
    int p = atomicAdd(&nflag, 1);
    flist[p] = tid;
  }
  __syncthreads();

  // exact fp64 re-scan for flagged rows. Wave-parallel + coalesced:
  // wave w scans cols w*128..+127; per col the wave loads the codebook row
  // as 64 x float4 (1 KB contiguous) and shuffle-reduces the fp64 distance.
  // L2 traffic = 1 MB per flagged row (was 4 MB scattered), 8x col-parallel.
  for (int f = 0; f < nflag; ++f) {
    int r = flist[f];
    if (tid < 64) {
      float4 v = *(const float4*)(x + (size_t)(row0 + r) * DDIM + tid * 4);
      xrow[tid * 4 + 0] = v.x; xrow[tid * 4 + 1] = v.y;
      xrow[tid * 4 + 2] = v.z; xrow[tid * 4 + 3] = v.w;
    }
    __syncthreads();
    float4 xv = *(const float4*)&xrow[lane * 4];
    double bestd = 1e300; int bi = 0;
    #pragma unroll 2
    for (int k = 0; k < 128; ++k) {
      int c = w * 128 + k;
      float4 cv = *(const float4*)(cb + (size_t)c * DDIM + lane * 4);
      double d0 = (double)xv.x - (double)cv.x; double s = d0 * d0;
      double d1 = (double)xv.y - (double)cv.y; s = fma(d1, d1, s);
      double d2 = (double)xv.z - (double)cv.z; s = fma(d2, d2, s);
      double d3 = (double)xv.w - (double)cv.w; s = fma(d3, d3, s);
      #pragma unroll
      for (int off = 32; off; off >>= 1) s += __shfl_down(s, off);
      if (lane == 0 && s < bestd) { bestd = s; bi = c; }  // increasing c: earliest tie
    }
    if (lane == 0) { rv[w] = bestd; ri[w] = bi; }
    __syncthreads();
    if (tid == 0) {
      double bv = rv[0]; int bix = ri[0];
      for (int ww = 1; ww < 8; ++ww)
        if (rv[ww] < bv || (rv[ww] == bv && ri[ww] < bix)) { bv = rv[ww]; bix = ri[ww]; }
      bidx[r] = bix;
    }
    __syncthreads();
  }

  if (tid < 128) idx_out[row0 + tid] = (float)bidx[tid];

  // ---- gather: z_q rows (exact fp32 copies) + loss partial ----
  float lsum = 0.f;
  #pragma unroll 4
  for (int it = 0; it < 16; ++it) {
    int g = tid + 512 * it;        // 8192 float4 groups = 128 rows x 64 groups
    int r = g >> 6;
    int c4 = (g & 63) << 2;
    int k = bidx[r] & (KCB - 1);
    float4 cv = *(const float4*)(cb + (size_t)k * DDIM + c4);
    float4 xv = *(const float4*)(x + (size_t)(row0 + r) * DDIM + c4);
    float d0 = cv.x - xv.x, d1 = cv.y - xv.y, d2 = cv.z - xv.z, d3 = cv.w - xv.w;
    lsum = fmaf(d0, d0, lsum); lsum = fmaf(d1, d1, lsum);
    lsum = fmaf(d2, d2, lsum); lsum = fmaf(d3, d3, lsum);
    *(float4*)(zq_out + (size_t)(row0 + r) * DDIM + c4) = cv;
  }
  #pragma unroll
  for (int off = 32; off; off >>= 1) lsum += __shfl_down(lsum, off);
  if (lane == 0) wred[w] = lsum;
  __syncthreads();
  if (tid == 0) {
    double ls = 0.0;
    #pragma unroll
    for (int ww = 0; ww < 8; ++ww) ls += (double)wred[ww];
    atomicAdd(sumsq, ls);
    int si = 0;
    #pragma unroll 8
    for (int r = 0; r < 128; ++r) si += bidx[r] & (KCB - 1);
    atomicAdd(sumidx, si);
  }
}

__global__ void finalize_kernel(const double* __restrict__ sumsq,
                                const int* __restrict__ sumidx,
                                float* __restrict__ out_loss,
                                float* __restrict__ out_perp) {
  // loss = mean(sg(zq)-x)^2 + 0.25*mean(zq-sg(x))^2 = 1.25 * MSE (fwd equal)
  double loss = 1.25 * (*sumsq) / 8388608.0;
  double e_min = (double)(*sumidx) / 32768.0;      // scalar mean of indices
  double perp = exp(-e_min * log(e_min + 1e-10));  // underflows to 0
  *out_loss = (float)loss;
  *out_perp = (float)perp;
}

extern "C" void kernel_launch(void* const* d_in, const int* in_sizes, int n_in,
                              void* d_out, int out_size, void* d_ws, size_t ws_size,
                              hipStream_t stream) {
  const float* x  = (const float*)d_in[0];   // [32768, 256] fp32
  const float* cb = (const float*)d_in[1];   // [1024, 256] fp32
  float* out = (float*)d_out;
  float* out_loss = out;                  // [0]
  float* out_zq   = out + 1;              // [1 .. 8388608]
  float* out_perp = out + 1 + 8388608;    // [8388609]
  float* out_idx  = out + 2 + 8388608;    // [8388610 ..]

  double*   sumsq  = (double*)d_ws;
  int*      sumidx = (int*)((char*)d_ws + 8);
  float*    cn     = (float*)((char*)d_ws + 16);      // 4 KB

  hipLaunchKernelGGL(init_kernel, dim3(1), dim3(1), 0, stream, sumsq, sumidx);
  hipLaunchKernelGGL(prep_kernel, dim3(KCB), dim3(64), 0, stream, cb, cn);
  hipLaunchKernelGGL(fused_kernel, dim3(NROWS / 128), dim3(512), 0, stream,
                     x, cb, cn, out_zq, out_idx, sumsq, sumidx);
  hipLaunchKernelGGL(finalize_kernel, dim3(1), dim3(1), 0, stream,
                     sumsq, sumidx, out_loss, out_perp);
}

// Round 3
// 162.791 us; speedup vs baseline: 1.8817x; 1.8817x over previous
//
#include <hip/hip_runtime.h>
#include <cmath>

// x[32768, 256] fp32, codebook[1024, 256] fp32. Outputs fp32 flat:
// loss(1), z_q(8388608), perplexity(1), indices(32768)
#define NROWS 32768
#define DDIM  256
#define KCB   1024

// Split-fp16 (hi+lo) 3-term dot: dist error ~1e-3 abs; TAU=0.02 is ~20x.
// Top-3 tracking: rows with v2-v1 < TAU get an fp64 pair-compare of the two
// candidates (cheap, wave-parallel); rows with v3-v1 < TAU (P ~ 2e-5) get a
// full fp64 1024-scan. The expensive scan is now a ~once-per-dataset event.
constexpr float TAU = 0.02f;
constexpr int BSTR = 264;      // validated conflict-free stride (528 B/row)

typedef _Float16 half8 __attribute__((ext_vector_type(8)));
typedef float floatx4 __attribute__((ext_vector_type(4)));

__global__ void init_kernel(double* __restrict__ sumsq, int* __restrict__ sumidx) {
  *sumsq = 0.0;
  *sumidx = 0;
}

// Exact codebook norms (fp64 -> fp32).
__global__ __launch_bounds__(64) void prep_kernel(const float* __restrict__ cb,
                                                  float* __restrict__ cn) {
  const int k = blockIdx.x, lane = threadIdx.x;
  float4 v = *(const float4*)(cb + (size_t)k * DDIM + lane * 4);
  double s = (double)v.x * v.x + (double)v.y * v.y
           + (double)v.z * v.z + (double)v.w * v.w;
  #pragma unroll
  for (int off = 32; off; off >>= 1) s += __shfl_down(s, off);
  if (lane == 0) cn[k] = (float)s;
}

// Block = 512 thr / 8 waves, 128 rows (16 rows/wave). Grid 256 = 1 block/CU.
// Stage = 32 codebook entries x 256 dims, {hi rows 0..31, lo rows 32..63}
// fp16 in 64xBSTR layout, double-buffered. hi/lo computed on the fly from
// fp32 cb. dot = a_hi*b_hi + a_lo*b_hi + a_hi*b_lo, each term in its OWN
// accumulator (3 independent 8-deep MFMA chains), summed in the epilogue.
__global__ __launch_bounds__(512, 2) void fused_kernel(
    const float* __restrict__ x,
    const float* __restrict__ cb,
    const float* __restrict__ cn,
    float* __restrict__ zq_out,
    float* __restrict__ idx_out,
    double* __restrict__ sumsq,
    int* __restrict__ sumidx) {
  __shared__ __align__(16) _Float16 bs[2][64 * BSTR];  // 2 x 33.8 KB tiles
  __shared__ float cn_lds[KCB];
  __shared__ int   bidx[128];    // best index
  __shared__ int   bidx2[128];   // second-best index
  __shared__ float m2s[128];     // v2 - v1
  __shared__ float m3s[128];     // v3 - v1
  __shared__ __align__(16) float xrow[DDIM];
  __shared__ int   plist[128];   // pair-recheck rows
  __shared__ int   flist[128];   // full-rescan rows
  __shared__ int   npair, nfull;
  __shared__ float wred[8];
  __shared__ double rv[8];
  __shared__ int    ri[8];

  const int tid = threadIdx.x;
  const int lane = tid & 63;
  const int w = tid >> 6;        // wave 0..7: rows w*16 .. +15
  const int q = lane >> 4;       // quad
  const int tx = lane & 15;
  const int row0 = blockIdx.x * 128;

  // ---- A fragments (hi+lo): lane holds x[row0+w*16+tx][s*32+q*8..+7] ----
  half8 a_hi[8], a_lo[8];
  {
    const float* xp = x + (size_t)(row0 + w * 16 + tx) * DDIM + q * 8;
    #pragma unroll
    for (int s = 0; s < 8; ++s) {
      float4 v0 = *(const float4*)(xp + s * 32);
      float4 v1 = *(const float4*)(xp + s * 32 + 4);
      half8 h, l;
      _Float16 t;
      t = (_Float16)v0.x; h[0] = t; l[0] = (_Float16)(v0.x - (float)t);
      t = (_Float16)v0.y; h[1] = t; l[1] = (_Float16)(v0.y - (float)t);
      t = (_Float16)v0.z; h[2] = t; l[2] = (_Float16)(v0.z - (float)t);
      t = (_Float16)v0.w; h[3] = t; l[3] = (_Float16)(v0.w - (float)t);
      t = (_Float16)v1.x; h[4] = t; l[4] = (_Float16)(v1.x - (float)t);
      t = (_Float16)v1.y; h[5] = t; l[5] = (_Float16)(v1.y - (float)t);
      t = (_Float16)v1.z; h[6] = t; l[6] = (_Float16)(v1.z - (float)t);
      t = (_Float16)v1.w; h[7] = t; l[7] = (_Float16)(v1.w - (float)t);
      a_hi[s] = h; a_lo[s] = l;
    }
  }
  #pragma unroll
  for (int i = 0; i < 2; ++i) cn_lds[tid + 512 * i] = cn[tid + 512 * i];
  if (tid == 0) { npair = 0; nfull = 0; }

  // stage ct covers entries ct*32..+31 (8192 floats). 32-B unit u = tid+512*i:
  // entry e = u>>5, dim chunk (u&31)*8..+7. Coalesced 32 B/thread loads.
  float4 vld[4];
  auto load_stage = [&](int ct) {
    #pragma unroll
    for (int i = 0; i < 2; ++i) {
      int u = tid + 512 * i;
      const float* p = cb + (size_t)ct * 8192 + (size_t)u * 8;
      vld[2 * i]     = *(const float4*)p;
      vld[2 * i + 1] = *(const float4*)(p + 4);
    }
  };
  auto write_stage = [&](int buf) {
    #pragma unroll
    for (int i = 0; i < 2; ++i) {
      int u = tid + 512 * i;
      int e = u >> 5, c = u & 31;
      float4 v0 = vld[2 * i], v1 = vld[2 * i + 1];
      half8 h, l;
      _Float16 t;
      t = (_Float16)v0.x; h[0] = t; l[0] = (_Float16)(v0.x - (float)t);
      t = (_Float16)v0.y; h[1] = t; l[1] = (_Float16)(v0.y - (float)t);
      t = (_Float16)v0.z; h[2] = t; l[2] = (_Float16)(v0.z - (float)t);
      t = (_Float16)v0.w; h[3] = t; l[3] = (_Float16)(v0.w - (float)t);
      t = (_Float16)v1.x; h[4] = t; l[4] = (_Float16)(v1.x - (float)t);
      t = (_Float16)v1.y; h[5] = t; l[5] = (_Float16)(v1.y - (float)t);
      t = (_Float16)v1.z; h[6] = t; l[6] = (_Float16)(v1.z - (float)t);
      t = (_Float16)v1.w; h[7] = t; l[7] = (_Float16)(v1.w - (float)t);
      *(half8*)&bs[buf][e * BSTR + c * 8] = h;         // hi rows 0..31
      *(half8*)&bs[buf][(32 + e) * BSTR + c * 8] = l;  // lo rows 32..63
    }
  };

  // top-3 values + top-2 indices per owned row r (ascending v1<=v2<=v3)
  float v1[4], v2[4], v3[4];
  int i1[4], i2[4];
  #pragma unroll
  for (int r = 0; r < 4; ++r) {
    v1[r] = INFINITY; v2[r] = INFINITY; v3[r] = INFINITY; i1[r] = 0; i2[r] = 0;
  }

  load_stage(0);
  for (int st = 0; st < 32; ++st) {
    const int buf = st & 1;
    write_stage(buf);            // consumes loads issued last iter (vmcnt wait)
    __syncthreads();             // tile visible; prev tile's readers done
    if (st + 1 < 32) load_stage(st + 1);   // in flight across compute(st)

    floatx4 ahh[2], alh[2], ahl[2];
    #pragma unroll
    for (int ci = 0; ci < 2; ++ci) {
      ahh[ci] = (floatx4){0.f, 0.f, 0.f, 0.f};
      alh[ci] = (floatx4){0.f, 0.f, 0.f, 0.f};
      ahl[ci] = (floatx4){0.f, 0.f, 0.f, 0.f};
    }

    #pragma unroll
    for (int s = 0; s < 8; ++s) {
      #pragma unroll
      for (int ci = 0; ci < 2; ++ci) {
        half8 bh = *(const half8*)&bs[buf][(ci * 16 + tx) * BSTR + (s * 4 + q) * 8];
        half8 bl = *(const half8*)&bs[buf][(32 + ci * 16 + tx) * BSTR + (s * 4 + q) * 8];
        ahh[ci] = __builtin_amdgcn_mfma_f32_16x16x32_f16(a_hi[s], bh, ahh[ci], 0, 0, 0);
        alh[ci] = __builtin_amdgcn_mfma_f32_16x16x32_f16(a_lo[s], bh, alh[ci], 0, 0, 0);
        ahl[ci] = __builtin_amdgcn_mfma_f32_16x16x32_f16(a_hi[s], bl, ahl[ci], 0, 0, 0);
      }
    }

    // epilogue: C/D layout col=lane&15, row=q*4+reg
    #pragma unroll
    for (int ci = 0; ci < 2; ++ci) {
      int col = st * 32 + ci * 16 + tx;
      float cnv = cn_lds[col];
      #pragma unroll
      for (int r = 0; r < 4; ++r) {
        float dot = ahh[ci][r] + alh[ci][r] + ahl[ci][r];
        float dist = cnv - 2.f * dot;
        if (dist < v1[r]) {
          v3[r] = v2[r]; v2[r] = v1[r]; i2[r] = i1[r];
          v1[r] = dist; i1[r] = col;
        } else if (dist < v2[r]) {
          v3[r] = v2[r]; v2[r] = dist; i2[r] = col;
        } else if (dist < v3[r]) {
          v3[r] = dist;
        }
      }
    }
  }

  // merge top-3 (+ top-2 idx) across the 16 tx-lanes of each quad
  #pragma unroll
  for (int off = 8; off; off >>= 1) {
    #pragma unroll
    for (int r = 0; r < 4; ++r) {
      float ov1 = __shfl_down(v1[r], off, 16);
      int   oi1 = __shfl_down(i1[r], off, 16);
      float ov2 = __shfl_down(v2[r], off, 16);
      int   oi2 = __shfl_down(i2[r], off, 16);
      float ov3 = __shfl_down(v3[r], off, 16);
      // merge two ascending triples; keep top-3 + top-2 indices
      bool takeo = (ov1 < v1[r]) || (ov1 == v1[r] && oi1 < i1[r]);
      float n1v = takeo ? ov1 : v1[r];
      int   n1i = takeo ? oi1 : i1[r];
      float l1 = takeo ? v1[r] : v2[r];
      int   l1i = takeo ? i1[r] : i2[r];
      float l2 = takeo ? v2[r] : v3[r];
      float r1 = takeo ? ov2 : ov1;
      int   r1i = takeo ? oi2 : oi1;
      float r2 = takeo ? ov3 : ov2;
      bool t2 = (r1 < l1) || (r1 == l1 && r1i < l1i);
      float n2v = t2 ? r1 : l1;
      int   n2i = t2 ? r1i : l1i;
      float n3v = t2 ? fminf(r2, l1) : fminf(l2, r1);
      v1[r] = n1v; i1[r] = n1i; v2[r] = n2v; i2[r] = n2i; v3[r] = n3v;
    }
  }
  if (tx == 0) {
    #pragma unroll
    for (int r = 0; r < 4; ++r) {
      int R = w * 16 + q * 4 + r;
      bidx[R]  = i1[r];
      bidx2[R] = i2[r];
      m2s[R] = v2[r] - v1[r];
      m3s[R] = v3[r] - v1[r];
    }
  }
  __syncthreads();

  if (tid < 128) {
    if (m3s[tid] < TAU) {                       // >=2 rivals within TAU: rare
      int p = atomicAdd(&nfull, 1);
      flist[p] = tid;
    } else if (m2s[tid] < TAU) {                // exactly one rival: pair check
      int p = atomicAdd(&npair, 1);
      plist[p] = tid;
    }
  }
  __syncthreads();

  // ---- full fp64 re-scan (P ~ 2e-5 per row; correctness net) ----
  for (int f = 0; f < nfull; ++f) {
    int r = flist[f];
    if (tid < 64) {
      float4 v = *(const float4*)(x + (size_t)(row0 + r) * DDIM + tid * 4);
      xrow[tid * 4 + 0] = v.x; xrow[tid * 4 + 1] = v.y;
      xrow[tid * 4 + 2] = v.z; xrow[tid * 4 + 3] = v.w;
    }
    __syncthreads();
    float4 xv = *(const float4*)&xrow[lane * 4];
    double bestd = 1e300; int bi = 0;
    for (int k = 0; k < 128; ++k) {
      int c = w * 128 + k;
      float4 cv = *(const float4*)(cb + (size_t)c * DDIM + lane * 4);
      double d0 = (double)xv.x - (double)cv.x; double s = d0 * d0;
      double d1 = (double)xv.y - (double)cv.y; s = fma(d1, d1, s);
      double d2 = (double)xv.z - (double)cv.z; s = fma(d2, d2, s);
      double d3 = (double)xv.w - (double)cv.w; s = fma(d3, d3, s);
      #pragma unroll
      for (int off = 32; off; off >>= 1) s += __shfl_down(s, off);
      if (lane == 0 && s < bestd) { bestd = s; bi = c; }  // increasing c: first tie
    }
    if (lane == 0) { rv[w] = bestd; ri[w] = bi; }
    __syncthreads();
    if (tid == 0) {
      double bv = rv[0]; int bix = ri[0];
      for (int ww = 1; ww < 8; ++ww)
        if (rv[ww] < bv || (rv[ww] == bv && ri[ww] < bix)) { bv = rv[ww]; bix = ri[ww]; }
      bidx[r] = bix;
    }
    __syncthreads();
  }

  // ---- fp64 pair-compare of {best, second}; waves take rows in parallel ----
  for (int f = w; f < npair; f += 8) {
    int r = plist[f];
    int cA = bidx[r], cB = bidx2[r];
    int c = (lane >= 32) ? cB : cA;
    int ld = lane & 31;                         // 32 lanes x 8 dims each
    const float* xp = x  + (size_t)(row0 + r) * DDIM + ld * 8;
    const float* cp = cb + (size_t)c * DDIM + ld * 8;
    double s = 0.0;
    #pragma unroll
    for (int j = 0; j < 8; j += 4) {
      float4 xv = *(const float4*)(xp + j);
      float4 cv = *(const float4*)(cp + j);
      double d0 = (double)xv.x - (double)cv.x; s = fma(d0, d0, s);
      double d1 = (double)xv.y - (double)cv.y; s = fma(d1, d1, s);
      double d2 = (double)xv.z - (double)cv.z; s = fma(d2, d2, s);
      double d3 = (double)xv.w - (double)cv.w; s = fma(d3, d3, s);
    }
    #pragma unroll
    for (int off = 16; off; off >>= 1) s += __shfl_xor(s, off);  // within 32-lane half
    double dA = __shfl(s, 0), dB = __shfl(s, 32);
    if (lane == 0) {
      bool takeB = (dB < dA) || (dB == dA && cB < cA);
      bidx[r] = takeB ? cB : cA;
    }
  }
  __syncthreads();

  if (tid < 128) idx_out[row0 + tid] = (float)bidx[tid];

  // ---- gather: z_q rows (exact fp32 copies) + loss partial ----
  float lsum = 0.f;
  #pragma unroll 4
  for (int it = 0; it < 16; ++it) {
    int g = tid + 512 * it;        // 8192 float4 groups = 128 rows x 64 groups
    int r = g >> 6;
    int c4 = (g & 63) << 2;
    int k = bidx[r] & (KCB - 1);
    float4 cv = *(const float4*)(cb + (size_t)k * DDIM + c4);
    float4 xv = *(const float4*)(x + (size_t)(row0 + r) * DDIM + c4);
    float d0 = cv.x - xv.x, d1 = cv.y - xv.y, d2 = cv.z - xv.z, d3 = cv.w - xv.w;
    lsum = fmaf(d0, d0, lsum); lsum = fmaf(d1, d1, lsum);
    lsum = fmaf(d2, d2, lsum); lsum = fmaf(d3, d3, lsum);
    *(float4*)(zq_out + (size_t)(row0 + r) * DDIM + c4) = cv;
  }
  #pragma unroll
  for (int off = 32; off; off >>= 1) lsum += __shfl_down(lsum, off);
  if (lane == 0) wred[w] = lsum;
  __syncthreads();
  if (tid == 0) {
    double ls = 0.0;
    #pragma unroll
    for (int ww = 0; ww < 8; ++ww) ls += (double)wred[ww];
    atomicAdd(sumsq, ls);
    int si = 0;
    #pragma unroll 8
    for (int r = 0; r < 128; ++r) si += bidx[r] & (KCB - 1);
    atomicAdd(sumidx, si);
  }
}

__global__ void finalize_kernel(const double* __restrict__ sumsq,
                                const int* __restrict__ sumidx,
                                float* __restrict__ out_loss,
                                float* __restrict__ out_perp) {
  // loss = mean(sg(zq)-x)^2 + 0.25*mean(zq-sg(x))^2 = 1.25 * MSE (fwd equal)
  double loss = 1.25 * (*sumsq) / 8388608.0;
  double e_min = (double)(*sumidx) / 32768.0;      // scalar mean of indices
  double perp = exp(-e_min * log(e_min + 1e-10));  // underflows to 0
  *out_loss = (float)loss;
  *out_perp = (float)perp;
}

extern "C" void kernel_launch(void* const* d_in, const int* in_sizes, int n_in,
                              void* d_out, int out_size, void* d_ws, size_t ws_size,
                              hipStream_t stream) {
  const float* x  = (const float*)d_in[0];   // [32768, 256] fp32
  const float* cb = (const float*)d_in[1];   // [1024, 256] fp32
  float* out = (float*)d_out;
  float* out_loss = out;                  // [0]
  float* out_zq   = out + 1;              // [1 .. 8388608]
  float* out_perp = out + 1 + 8388608;    // [8388609]
  float* out_idx  = out + 2 + 8388608;    // [8388610 ..]

  double*   sumsq  = (double*)d_ws;
  int*      sumidx = (int*)((char*)d_ws + 8);
  float*    cn     = (float*)((char*)d_ws + 16);      // 4 KB

  hipLaunchKernelGGL(init_kernel, dim3(1), dim3(1), 0, stream, sumsq, sumidx);
  hipLaunchKernelGGL(prep_kernel, dim3(KCB), dim3(64), 0, stream, cb, cn);
  hipLaunchKernelGGL(fused_kernel, dim3(NROWS / 128), dim3(512), 0, stream,
                     x, cb, cn, out_zq, out_idx, sumsq, sumidx);
  hipLaunchKernelGGL(finalize_kernel, dim3(1), dim3(1), 0, stream,
                     sumsq, sumidx, out_loss, out_perp);
}